// Round 1
// baseline (617.605 us; speedup 1.0000x reference)
//
#include <hip/hip_runtime.h>
#include <stdint.h>

// ---------------------------------------------------------------------------
// DynamicConv (CondConv x2 + PReLU + self-routing + 1x1 out), MI355X gfx950
// Strategy: fp16 MFMA implicit GEMM with shifted-window trick on padded NHWC.
// ---------------------------------------------------------------------------

typedef _Float16 f16_t;
typedef _Float16 f16x8 __attribute__((ext_vector_type(8)));
typedef _Float16 f16x4 __attribute__((ext_vector_type(4)));
typedef float    f32x4 __attribute__((ext_vector_type(4)));

#define B_   8
#define R_   4
#define C_   64
#define C2_  128
#define H_   128
#define W_   128
#define E_   8
#define RF_  256
#define WP_  130   // padded width: guard cols at w'=0 and w'=129 (zeros)

__device__ __forceinline__ f32x4 mfma16(f16x8 a, f16x8 b, f32x4 c) {
  return __builtin_amdgcn_mfma_f32_16x16x32_f16(a, b, c, 0, 0, 0);
}

// ---------- routing weights: rw[r*8+b][e] = sigmoid(routing@W + b) ----------
__global__ void k_rw(const float* __restrict__ routing, const float* __restrict__ rW,
                     const float* __restrict__ rB, float* __restrict__ rw) {
  int t = threadIdx.x;                 // 256 = R*B*E
  int e = t & 7, b = (t >> 3) & 7, r = t >> 6;
  float acc = rB[e];
  for (int f = 0; f < RF_; ++f)
    acc += routing[(b*R_ + r)*RF_ + f] * rW[f*E_ + e];
  rw[(r*B_ + b)*E_ + e] = 1.0f / (1.0f + __expf(-acc));
}

// ---------- x: NCHW f32 -> padded NHWC f16 (guard cols zeroed) ----------
__global__ void k_xt(const float* __restrict__ x, f16_t* __restrict__ xbt) {
  int wh = blockIdx.x, h = blockIdx.y, b = blockIdx.z;
  int t = threadIdx.x;
  int w0 = wh * 64;
  __shared__ float tile[64][65];
  #pragma unroll
  for (int rep = 0; rep < 16; ++rep) {
    int idx = rep*256 + t;
    int c = idx >> 6, w = idx & 63;
    tile[c][w] = x[((size_t)(b*C_ + c)*H_ + h)*W_ + w0 + w];
  }
  __syncthreads();
  #pragma unroll
  for (int rep = 0; rep < 16; ++rep) {
    int idx = rep*256 + t;
    int w = idx >> 6, c = idx & 63;
    xbt[((size_t)(b*H_ + h)*WP_ + (w0 + w + 1))*C_ + c] = (f16_t)tile[c][w];
  }
  if (t < 64) {
    if (wh == 0) xbt[((size_t)(b*H_ + h)*WP_ + 0)*C_ + t]   = (f16_t)0.0f;
    else         xbt[((size_t)(b*H_ + h)*WP_ + 129)*C_ + t] = (f16_t)0.0f;
  }
}

// ---------- mix1: w1m[rb][co][k], k = s*64 + c,  s = kh*3+kw ----------
__global__ void k_mix1(const float* __restrict__ rw, const float* __restrict__ W1,
                       f16_t* __restrict__ w1m) {
  int gid = blockIdx.x*256 + threadIdx.x;    // 589824 total
  int cq = gid & 15;
  int s  = (gid >> 4) % 9;
  int t2 = (gid >> 4) / 9;
  int co = t2 & 127;
  int rb = t2 >> 7;                          // 0..31
  float o0=0.f,o1=0.f,o2=0.f,o3=0.f;
  #pragma unroll
  for (int e = 0; e < E_; ++e) {
    float rv = rw[rb*E_ + e];
    const float* wp = W1 + (size_t)((e*C2_ + co)*C_ + cq*4)*9 + s;
    o0 += rv*wp[0]; o1 += rv*wp[9]; o2 += rv*wp[18]; o3 += rv*wp[27];
  }
  f16x4 pk; pk[0]=(f16_t)o0; pk[1]=(f16_t)o1; pk[2]=(f16_t)o2; pk[3]=(f16_t)o3;
  *(f16x4*)&w1m[(size_t)(rb*C2_ + co)*576 + s*64 + cq*4] = pk;
}

// ---------- srw[b][e] = (pooled/HW) @ sr_W + sr_b  (no sigmoid) ----------
__global__ void k_srw(const float* __restrict__ pooled, const float* __restrict__ srW,
                      const float* __restrict__ srb, float* __restrict__ srw) {
  int t = threadIdx.x;                 // 64 = B*E
  int b = t >> 3, e = t & 7;
  float acc = srb[e];
  for (int c = 0; c < C2_; ++c)
    acc += pooled[b*C2_ + c] * (1.0f/16384.0f) * srW[c*E_ + e];
  srw[b*E_ + e] = acc;
}

// ---------- mix2: w2m[b][co][k2], k2 = s*128 + c2 ----------
__global__ void k_mix2(const float* __restrict__ srw, const float* __restrict__ W2,
                       f16_t* __restrict__ w2m) {
  int gid = blockIdx.x*256 + threadIdx.x;    // 147456 total
  int c2q = gid & 31;
  int s   = (gid >> 5) % 9;
  int t2  = (gid >> 5) / 9;
  int co  = t2 & 63;
  int b   = t2 >> 6;
  float o0=0.f,o1=0.f,o2=0.f,o3=0.f;
  #pragma unroll
  for (int e = 0; e < E_; ++e) {
    float rv = srw[b*E_ + e];
    const float* wp = W2 + (size_t)((e*C_ + co)*C2_ + c2q*4)*9 + s;
    o0 += rv*wp[0]; o1 += rv*wp[9]; o2 += rv*wp[18]; o3 += rv*wp[27];
  }
  f16x4 pk; pk[0]=(f16_t)o0; pk[1]=(f16_t)o1; pk[2]=(f16_t)o2; pk[3]=(f16_t)o3;
  *(f16x4*)&w2m[(size_t)(b*C_ + co)*1152 + s*C2_ + c2q*4] = pk;
}

// ---------- conv1: xc = PReLU(condconv(x, w1m)) in padded NHWC, + pooled ----
// GEMM per (b, h-row): M=128(co) x N=128(w) x K=576. 4 waves, 64x64 wave tile.
__global__ __launch_bounds__(256, 2) void k_conv1(
    const f16_t* __restrict__ xbt, const f16_t* __restrict__ w1m,
    const float* __restrict__ pa, f16_t* __restrict__ xct,
    float* __restrict__ pooled, int r)
{
  const int h = blockIdx.x, b = blockIdx.y;
  const int tid = threadIdx.x;
  const int lane = tid & 63;
  const int wid = tid >> 6;
  const int wm = wid >> 1, wn = wid & 1;
  const int l15 = lane & 15, l4 = lane >> 4;
  __shared__ __align__(16) f16_t lA[C2_*96];   // [co][dw(3)][kk(32)]
  __shared__ __align__(16) f16_t lB[132*32];   // [pix 0..129][kk]
  const f32x4 vzero = {0.f,0.f,0.f,0.f};
  f32x4 acc[4][4];
  #pragma unroll
  for (int i=0;i<4;++i)
    #pragma unroll
    for (int j=0;j<4;++j) acc[i][j] = vzero;
  const int rb = r*B_ + b;
  const f16_t* w1base = w1m + (size_t)rb*C2_*576;

  for (int dh = -1; dh <= 1; ++dh) {
    const int hh = h + dh;
    if (hh < 0 || hh >= H_) continue;         // zero padding in h -> skip
    const f16_t* xrow = xbt + (size_t)(b*H_ + hh)*WP_*C_;
    for (int cb = 0; cb < 2; ++cb) {
      __syncthreads();
      // stage A: 1536 x 16B slots, linear [co][dwi][hf]
      #pragma unroll
      for (int it = 0; it < 6; ++it) {
        int i = it*256 + tid;
        int co = i / 12, rem = i % 12;
        int dwi = rem >> 2, hf = rem & 3;
        const uint4 v = *(const uint4*)(w1base + (size_t)co*576
                          + ((dh+1)*3 + dwi)*64 + cb*32 + hf*8);
        *(uint4*)((char*)lA + i*16) = v;
      }
      // stage B: 520 x 16B slots = [pix 0..129][q], guards included (zeros)
      for (int i = tid; i < 520; i += 256) {
        int pix = i >> 2, q = i & 3;
        const uint4 v = *(const uint4*)(xrow + pix*C_ + cb*32 + q*8);
        *(uint4*)((char*)lB + i*16) = v;
      }
      __syncthreads();
      #pragma unroll
      for (int dw = 0; dw < 3; ++dw) {
        f16x8 af[4], bfv[4];
        #pragma unroll
        for (int fm = 0; fm < 4; ++fm)
          af[fm] = *(const f16x8*)&lA[(wm*64 + fm*16 + l15)*96 + dw*32 + l4*8];
        #pragma unroll
        for (int fn = 0; fn < 4; ++fn)
          bfv[fn] = *(const f16x8*)&lB[(dw + wn*64 + fn*16 + l15)*32 + l4*8];
        #pragma unroll
        for (int fm = 0; fm < 4; ++fm)
          #pragma unroll
          for (int fn = 0; fn < 4; ++fn)
            acc[fm][fn] = mfma16(af[fm], bfv[fn], acc[fm][fn]);
      }
    }
  }

  // epilogue: PReLU, write xc (NHWC f16), accumulate pooled sums
  const float a = pa[0];
  float ps[4][4];
  #pragma unroll
  for (int fm=0;fm<4;++fm)
    #pragma unroll
    for (int j=0;j<4;++j) ps[fm][j] = 0.f;

  f16_t* xcbase = xct + (size_t)(b*H_ + h)*WP_*C2_;
  #pragma unroll
  for (int fm = 0; fm < 4; ++fm) {
    const int chb = wm*64 + fm*16 + l4*4;     // D row = (lane>>4)*4 + reg
    #pragma unroll
    for (int fn = 0; fn < 4; ++fn) {
      const int w = wn*64 + fn*16 + l15;      // D col = lane&15
      f16x4 pk;
      #pragma unroll
      for (int j = 0; j < 4; ++j) {
        float v = acc[fm][fn][j];
        v = (v >= 0.f) ? v : a*v;
        ps[fm][j] += v;
        pk[j] = (f16_t)v;
      }
      *(f16x4*)&xcbase[(size_t)(w+1)*C2_ + chb] = pk;
    }
  }
  #pragma unroll
  for (int fm = 0; fm < 4; ++fm)
    #pragma unroll
    for (int j = 0; j < 4; ++j) {
      float s = ps[fm][j];
      s += __shfl_xor(s, 1, 64);
      s += __shfl_xor(s, 2, 64);
      s += __shfl_xor(s, 4, 64);
      s += __shfl_xor(s, 8, 64);
      if (l15 == 0)
        atomicAdd(&pooled[b*C2_ + wm*64 + fm*16 + l4*4 + j], s);
    }
  // zero the guard columns of this (b,h) row
  if (tid < C2_) {
    xcbase[(size_t)0*C2_   + tid] = (f16_t)0.f;
    xcbase[(size_t)129*C2_ + tid] = (f16_t)0.f;
  }
}

// ---------- conv2 + PReLU + 1x1 Wout reduce -> out[b][r][h][w] ----------
// GEMM per (b, h-row): M=64(co) x N=128(w) x K=1152. 4 waves, 64x32 wave tile.
__global__ __launch_bounds__(256, 2) void k_conv2(
    const f16_t* __restrict__ xct, const f16_t* __restrict__ w2m,
    const float* __restrict__ pa, const float* __restrict__ Wout,
    const float* __restrict__ bout, float* __restrict__ out, int r)
{
  const int h = blockIdx.x, b = blockIdx.y;
  const int tid = threadIdx.x;
  const int lane = tid & 63;
  const int wid = tid >> 6;
  const int n0 = wid * 32;
  const int l15 = lane & 15, l4 = lane >> 4;
  __shared__ __align__(16) f16_t lA[C_*96];    // [co][dw(3)][kk(32)]
  __shared__ __align__(16) f16_t lB[132*32];   // [pix][kk]
  const f32x4 vzero = {0.f,0.f,0.f,0.f};
  f32x4 acc[4][2];
  #pragma unroll
  for (int i=0;i<4;++i) { acc[i][0] = vzero; acc[i][1] = vzero; }
  const f16_t* w2base = w2m + (size_t)b*C_*1152;

  for (int dh = -1; dh <= 1; ++dh) {
    const int hh = h + dh;
    if (hh < 0 || hh >= H_) continue;
    const f16_t* xrow = xct + (size_t)(b*H_ + hh)*WP_*C2_;
    for (int cb = 0; cb < 4; ++cb) {
      __syncthreads();
      #pragma unroll
      for (int it = 0; it < 3; ++it) {        // 768 slots
        int i = it*256 + tid;
        int co = i / 12, rem = i % 12;
        int dwi = rem >> 2, hf = rem & 3;
        const uint4 v = *(const uint4*)(w2base + (size_t)co*1152
                          + ((dh+1)*3 + dwi)*C2_ + cb*32 + hf*8);
        *(uint4*)((char*)lA + i*16) = v;
      }
      for (int i = tid; i < 520; i += 256) {
        int pix = i >> 2, q = i & 3;
        const uint4 v = *(const uint4*)(xrow + pix*C2_ + cb*32 + q*8);
        *(uint4*)((char*)lB + i*16) = v;
      }
      __syncthreads();
      #pragma unroll
      for (int dw = 0; dw < 3; ++dw) {
        f16x8 af[4], bfv[2];
        #pragma unroll
        for (int fm = 0; fm < 4; ++fm)
          af[fm] = *(const f16x8*)&lA[(fm*16 + l15)*96 + dw*32 + l4*8];
        #pragma unroll
        for (int fn = 0; fn < 2; ++fn)
          bfv[fn] = *(const f16x8*)&lB[(dw + n0 + fn*16 + l15)*32 + l4*8];
        #pragma unroll
        for (int fm = 0; fm < 4; ++fm)
          #pragma unroll
          for (int fn = 0; fn < 2; ++fn)
            acc[fm][fn] = mfma16(af[fm], bfv[fn], acc[fm][fn]);
      }
    }
  }

  // epilogue: PReLU + 1x1 conv (Wout) reduced in-register + cross-lane
  const float a  = pa[0];
  const float bo = bout[0];
  float wr[4][4];
  #pragma unroll
  for (int fm = 0; fm < 4; ++fm)
    #pragma unroll
    for (int j = 0; j < 4; ++j)
      wr[fm][j] = Wout[fm*16 + l4*4 + j];
  float sv[2];
  #pragma unroll
  for (int fn = 0; fn < 2; ++fn) {
    float s = 0.f;
    #pragma unroll
    for (int fm = 0; fm < 4; ++fm)
      #pragma unroll
      for (int j = 0; j < 4; ++j) {
        float v = acc[fm][fn][j];
        v = (v >= 0.f) ? v : a*v;
        s += wr[fm][j]*v;
      }
    s += __shfl_xor(s, 16, 64);
    s += __shfl_xor(s, 32, 64);
    sv[fn] = s + bo;
  }
  if (lane < 16) {
    float* orow = out + (size_t)((b*R_ + r)*H_ + h)*W_;
    orow[n0 + lane]      = sv[0];
    orow[n0 + 16 + lane] = sv[1];
  }
}

// ---------------------------------------------------------------------------
extern "C" void kernel_launch(void* const* d_in, const int* in_sizes, int n_in,
                              void* d_out, int out_size, void* d_ws, size_t ws_size,
                              hipStream_t stream) {
  (void)in_sizes; (void)n_in; (void)out_size; (void)ws_size;
  const float* x       = (const float*)d_in[0];
  const float* routing = (const float*)d_in[1];
  const float* rW      = (const float*)d_in[2];
  const float* rB      = (const float*)d_in[3];
  const float* W1      = (const float*)d_in[4];
  const float* pa      = (const float*)d_in[5];
  const float* W2      = (const float*)d_in[6];
  const float* srW     = (const float*)d_in[7];
  const float* srb     = (const float*)d_in[8];
  const float* Wout    = (const float*)d_in[9];
  const float* bout    = (const float*)d_in[10];
  float* out = (float*)d_out;

  char* ws = (char*)d_ws;
  size_t off = 0;
  f16_t* xbt = (f16_t*)(ws + off); off += (size_t)B_*H_*WP_*C_*2;   // 17,039,360
  f16_t* w1m = (f16_t*)(ws + off); off += (size_t)R_*B_*C2_*576*2;  //  4,718,592
  f16_t* xct = (f16_t*)(ws + off); off += (size_t)B_*H_*WP_*C2_*2;  // 34,078,720
  f16_t* w2m = (f16_t*)(ws + off); off += (size_t)B_*C_*1152*2;     //  1,179,648
  float* rw     = (float*)(ws + off); off += (size_t)R_*B_*E_*4;
  float* pooled = (float*)(ws + off); off += (size_t)B_*C2_*4;
  float* srwv   = (float*)(ws + off); off += (size_t)B_*E_*4;
  // total ~57.0 MB of d_ws

  k_rw  <<<1, 256, 0, stream>>>(routing, rW, rB, rw);
  k_xt  <<<dim3(2, H_, B_), 256, 0, stream>>>(x, xbt);
  k_mix1<<<2304, 256, 0, stream>>>(rw, W1, w1m);
  for (int r = 0; r < R_; ++r) {
    hipMemsetAsync(pooled, 0, B_*C2_*4, stream);
    k_conv1<<<dim3(H_, B_), 256, 0, stream>>>(xbt, w1m, pa, xct, pooled, r);
    k_srw  <<<1, 64, 0, stream>>>(pooled, srW, srb, srwv);
    k_mix2 <<<576, 256, 0, stream>>>(srwv, W2, w2m);
    k_conv2<<<dim3(H_, B_), 256, 0, stream>>>(xct, w2m, pa, Wout, bout, out, r);
  }
}

// Round 2
// 429.653 us; speedup vs baseline: 1.4375x; 1.4375x over previous
//
#include <hip/hip_runtime.h>
#include <stdint.h>

// ---------------------------------------------------------------------------
// DynamicConv (CondConv x2 + PReLU + self-routing + 1x1 out), MI355X gfx950
// R2: 4-row x 128co macro-tiles, 8 waves, padded conflict-free LDS strides,
//     weights staged once per block, fused srw into mix2.
// ---------------------------------------------------------------------------

typedef _Float16 f16_t;
typedef _Float16 f16x8 __attribute__((ext_vector_type(8)));
typedef _Float16 f16x4 __attribute__((ext_vector_type(4)));
typedef float    f32x4 __attribute__((ext_vector_type(4)));

#define B_   8
#define R_   4
#define C_   64
#define C2_  128
#define H_   128
#define W_   128
#define E_   8
#define RF_  256
#define WP_  130   // padded width: guard cols at pix 0 and 129 (zeros)

#define A_PITCH 296   // f16 per co row: 9 taps * 32 ch + 8 pad  (37 slots, 37%8=5)
#define B_PITCH 40    // f16 per (row,pix) unit: 32 ch + 8 pad   (5 slots, free)

__device__ __forceinline__ f32x4 mfma16(f16x8 a, f16x8 b, f32x4 c) {
  return __builtin_amdgcn_mfma_f32_16x16x32_f16(a, b, c, 0, 0, 0);
}

// ---------- routing weights + zero pooled[4][B][C2] ----------
__global__ void k_rw(const float* __restrict__ routing, const float* __restrict__ rW,
                     const float* __restrict__ rB, float* __restrict__ rw,
                     float* __restrict__ pooled4) {
  int t = threadIdx.x;                 // 256 = R*B*E
  #pragma unroll
  for (int i = 0; i < 16; ++i) pooled4[i*256 + t] = 0.f;
  int e = t & 7, b = (t >> 3) & 7, r = t >> 6;
  float acc = rB[e];
  for (int f = 0; f < RF_; ++f)
    acc += routing[(b*R_ + r)*RF_ + f] * rW[f*E_ + e];
  rw[(r*B_ + b)*E_ + e] = 1.0f / (1.0f + __expf(-acc));
}

// ---------- x: NCHW f32 -> padded NHWC f16 (guard cols zeroed) ----------
__global__ void k_xt(const float* __restrict__ x, f16_t* __restrict__ xbt) {
  int wh = blockIdx.x, h = blockIdx.y, b = blockIdx.z;
  int t = threadIdx.x;
  int w0 = wh * 64;
  __shared__ float tile[64][65];
  #pragma unroll
  for (int rep = 0; rep < 16; ++rep) {
    int idx = rep*256 + t;
    int c = idx >> 6, w = idx & 63;
    tile[c][w] = x[((size_t)(b*C_ + c)*H_ + h)*W_ + w0 + w];
  }
  __syncthreads();
  #pragma unroll
  for (int rep = 0; rep < 16; ++rep) {
    int idx = rep*256 + t;
    int w = idx >> 6, c = idx & 63;
    xbt[((size_t)(b*H_ + h)*WP_ + (w0 + w + 1))*C_ + c] = (f16_t)tile[c][w];
  }
  if (t < 64) {
    if (wh == 0) xbt[((size_t)(b*H_ + h)*WP_ + 0)*C_ + t]   = (f16_t)0.0f;
    else         xbt[((size_t)(b*H_ + h)*WP_ + 129)*C_ + t] = (f16_t)0.0f;
  }
}

// ---------- mix1: w1m[rb][cb2][co128][s9][ch32] ----------
__global__ void k_mix1(const float* __restrict__ rw, const float* __restrict__ W1,
                       f16_t* __restrict__ w1m) {
  int gid = blockIdx.x*256 + threadIdx.x;    // 589824 total
  int cq = gid & 15;
  int s  = (gid >> 4) % 9;
  int t2 = (gid >> 4) / 9;
  int co = t2 & 127;
  int rb = t2 >> 7;                          // 0..31
  float o0=0.f,o1=0.f,o2=0.f,o3=0.f;
  #pragma unroll
  for (int e = 0; e < E_; ++e) {
    float rv = rw[rb*E_ + e];
    const float* wp = W1 + (size_t)((e*C2_ + co)*C_ + cq*4)*9 + s;
    o0 += rv*wp[0]; o1 += rv*wp[9]; o2 += rv*wp[18]; o3 += rv*wp[27];
  }
  f16x4 pk; pk[0]=(f16_t)o0; pk[1]=(f16_t)o1; pk[2]=(f16_t)o2; pk[3]=(f16_t)o3;
  int cb = cq >> 3, cp = (cq & 7)*4;
  *(f16x4*)&w1m[((size_t)((rb*2 + cb)*128 + co))*288 + s*32 + cp] = pk;
}

// ---------- mix2 (+inline srw): w2m[b][cb4][co64][s9][ch32] ----------
__global__ void k_mix2(const float* __restrict__ pooled_r, const float* __restrict__ srW,
                       const float* __restrict__ srb, const float* __restrict__ W2,
                       f16_t* __restrict__ w2m) {
  __shared__ float sw[64];
  int t = threadIdx.x;
  if (t < 64) {
    int b = t >> 3, e = t & 7;
    float acc = srb[e];
    for (int c = 0; c < C2_; ++c)
      acc += pooled_r[b*C2_ + c] * (1.0f/16384.0f) * srW[c*E_ + e];
    sw[t] = acc;
  }
  __syncthreads();
  int gid = blockIdx.x*256 + t;              // 147456 total
  int c2q = gid & 31;
  int s   = (gid >> 5) % 9;
  int t2  = (gid >> 5) / 9;
  int co  = t2 & 63;
  int b   = t2 >> 6;
  float o0=0.f,o1=0.f,o2=0.f,o3=0.f;
  #pragma unroll
  for (int e = 0; e < E_; ++e) {
    float rv = sw[b*E_ + e];
    const float* wp = W2 + (size_t)((e*C_ + co)*C2_ + c2q*4)*9 + s;
    o0 += rv*wp[0]; o1 += rv*wp[9]; o2 += rv*wp[18]; o3 += rv*wp[27];
  }
  f16x4 pk; pk[0]=(f16_t)o0; pk[1]=(f16_t)o1; pk[2]=(f16_t)o2; pk[3]=(f16_t)o3;
  int cb = c2q >> 3, cp = (c2q & 7)*4;
  *(f16x4*)&w2m[((size_t)((b*4 + cb)*64 + co))*288 + s*32 + cp] = pk;
}

// ---------- conv1: per block (b, 4 rows): M=128co x N=512pix x K=576 ----------
__global__ __launch_bounds__(512, 2) void k_conv1(
    const f16_t* __restrict__ xbt, const f16_t* __restrict__ w1m,
    const float* __restrict__ pa, f16_t* __restrict__ xct,
    float* __restrict__ pooled_r, int r)
{
  const int b  = blockIdx.y;
  const int h0 = blockIdx.x * 4;
  const int tid = threadIdx.x;
  const int lane = tid & 63;
  const int wid = tid >> 6;
  const int wm = wid >> 2, wn = wid & 3;      // wave: co-half, output row
  const int l15 = lane & 15, l4 = lane >> 4;
  __shared__ __align__(16) f16_t lA[128 * A_PITCH];  // 75,776 B
  __shared__ __align__(16) f16_t lB[780 * B_PITCH];  // 62,400 B
  const f32x4 vzero = {0.f,0.f,0.f,0.f};
  f32x4 acc[4][8];
  #pragma unroll
  for (int i=0;i<4;++i)
    #pragma unroll
    for (int j=0;j<8;++j) acc[i][j] = vzero;
  const int rb = r*B_ + b;
  const f16_t* w1base = w1m + (size_t)rb*2*128*288;
  const f16_t* xb = xbt + (size_t)b*H_*WP_*C_;

  for (int cb = 0; cb < 2; ++cb) {
    __syncthreads();
    // stage A: 128co x 288 f16 = 4608 x 16B slots
    #pragma unroll
    for (int it = 0; it < 9; ++it) {
      int i = it*512 + tid;
      int co = i / 36, u = i - co*36;
      uint4 v = *(const uint4*)(w1base + ((size_t)(cb*128 + co))*288 + u*8);
      *(uint4*)&lA[co*A_PITCH + u*8] = v;
    }
    // stage B: 6 rows x 130 pix x 32 ch = 3120 x 16B slots (zero OOB rows)
    for (int i = tid; i < 3120; i += 512) {
      int rp = i >> 2, q = i & 3;
      int wrw = rp / 130, pix = rp - wrw*130;
      int hh = h0 - 1 + wrw;
      uint4 v = {0u,0u,0u,0u};
      if (hh >= 0 && hh < H_)
        v = *(const uint4*)(xb + ((size_t)hh*WP_ + pix)*C_ + cb*32 + q*8);
      *(uint4*)&lB[rp*B_PITCH + q*8] = v;
    }
    __syncthreads();
    #pragma unroll
    for (int dh = 0; dh < 3; ++dh) {
      #pragma unroll
      for (int dw = 0; dw < 3; ++dw) {
        const int s = dh*3 + dw;
        f16x8 af[4], bf[8];
        #pragma unroll
        for (int fm = 0; fm < 4; ++fm)
          af[fm] = *(const f16x8*)&lA[(wm*64 + fm*16 + l15)*A_PITCH + s*32 + l4*8];
        #pragma unroll
        for (int fn = 0; fn < 8; ++fn)
          bf[fn] = *(const f16x8*)&lB[((wn + dh)*130 + fn*16 + l15 + dw)*B_PITCH + l4*8];
        #pragma unroll
        for (int fm = 0; fm < 4; ++fm)
          #pragma unroll
          for (int fn = 0; fn < 8; ++fn)
            acc[fm][fn] = mfma16(af[fm], bf[fn], acc[fm][fn]);
      }
    }
  }

  // epilogue: PReLU, write xc row (NHWC f16), accumulate pooled sums
  const float a = pa[0];
  float ps[4][4];
  #pragma unroll
  for (int fm=0;fm<4;++fm)
    #pragma unroll
    for (int j=0;j<4;++j) ps[fm][j] = 0.f;

  f16_t* xrow = xct + ((size_t)(b*H_ + h0 + wn)*WP_)*C2_;
  #pragma unroll
  for (int fm = 0; fm < 4; ++fm) {
    const int chb = wm*64 + fm*16 + l4*4;
    #pragma unroll
    for (int fn = 0; fn < 8; ++fn) {
      const int w = fn*16 + l15;
      f16x4 pk;
      #pragma unroll
      for (int j = 0; j < 4; ++j) {
        float v = acc[fm][fn][j];
        v = (v >= 0.f) ? v : a*v;
        ps[fm][j] += v;
        pk[j] = (f16_t)v;
      }
      *(f16x4*)&xrow[(size_t)(w + 1)*C2_ + chb] = pk;
    }
  }
  #pragma unroll
  for (int fm = 0; fm < 4; ++fm)
    #pragma unroll
    for (int j = 0; j < 4; ++j) {
      float s = ps[fm][j];
      s += __shfl_xor(s, 1, 64);
      s += __shfl_xor(s, 2, 64);
      s += __shfl_xor(s, 4, 64);
      s += __shfl_xor(s, 8, 64);
      if (l15 == 0)
        atomicAdd(&pooled_r[b*C2_ + wm*64 + fm*16 + l4*4 + j], s);
    }
  // zero the guard columns of the 4 rows
  {
    int row = tid >> 7, ch = tid & 127;
    f16_t* g = xct + ((size_t)(b*H_ + h0 + row)*WP_)*C2_;
    g[ch] = (f16_t)0.f;
    g[(size_t)129*C2_ + ch] = (f16_t)0.f;
  }
}

// ---------- conv2 + PReLU + 1x1 Wout: per block (b, 4 rows): 64co x 512 x 1152 ----
__global__ __launch_bounds__(512, 2) void k_conv2(
    const f16_t* __restrict__ xct, const f16_t* __restrict__ w2m,
    const float* __restrict__ pa, const float* __restrict__ Wout,
    const float* __restrict__ bout, float* __restrict__ out, int r)
{
  const int b  = blockIdx.y;
  const int h0 = blockIdx.x * 4;
  const int tid = threadIdx.x;
  const int lane = tid & 63;
  const int wid = tid >> 6;
  const int wrow = wid >> 1, whalf = wid & 1;  // wave: output row, pixel half
  const int l15 = lane & 15, l4 = lane >> 4;
  __shared__ __align__(16) f16_t lA[64 * A_PITCH];   // 37,888 B
  __shared__ __align__(16) f16_t lB[780 * B_PITCH];  // 62,400 B
  const f32x4 vzero = {0.f,0.f,0.f,0.f};
  f32x4 acc[4][4];
  #pragma unroll
  for (int i=0;i<4;++i)
    #pragma unroll
    for (int j=0;j<4;++j) acc[i][j] = vzero;
  const f16_t* w2base = w2m + (size_t)b*4*64*288;
  const f16_t* xb = xct + (size_t)b*H_*WP_*C2_;

  for (int cb = 0; cb < 4; ++cb) {
    __syncthreads();
    // stage A: 64co x 288 f16 = 2304 slots
    #pragma unroll
    for (int it = 0; it < 5; ++it) {
      int i = it*512 + tid;
      if (i < 2304) {
        int co = i / 36, u = i - co*36;
        uint4 v = *(const uint4*)(w2base + ((size_t)(cb*64 + co))*288 + u*8);
        *(uint4*)&lA[co*A_PITCH + u*8] = v;
      }
    }
    // stage B: 6 rows x 130 pix x 32 ch
    for (int i = tid; i < 3120; i += 512) {
      int rp = i >> 2, q = i & 3;
      int wrw = rp / 130, pix = rp - wrw*130;
      int hh = h0 - 1 + wrw;
      uint4 v = {0u,0u,0u,0u};
      if (hh >= 0 && hh < H_)
        v = *(const uint4*)(xb + ((size_t)hh*WP_ + pix)*C2_ + cb*32 + q*8);
      *(uint4*)&lB[rp*B_PITCH + q*8] = v;
    }
    __syncthreads();
    #pragma unroll
    for (int dh = 0; dh < 3; ++dh) {
      #pragma unroll
      for (int dw = 0; dw < 3; ++dw) {
        const int s = dh*3 + dw;
        f16x8 af[4], bf[4];
        #pragma unroll
        for (int fm = 0; fm < 4; ++fm)
          af[fm] = *(const f16x8*)&lA[(fm*16 + l15)*A_PITCH + s*32 + l4*8];
        #pragma unroll
        for (int fn = 0; fn < 4; ++fn)
          bf[fn] = *(const f16x8*)&lB[((wrow + dh)*130 + whalf*64 + fn*16 + l15 + dw)*B_PITCH + l4*8];
        #pragma unroll
        for (int fm = 0; fm < 4; ++fm)
          #pragma unroll
          for (int fn = 0; fn < 4; ++fn)
            acc[fm][fn] = mfma16(af[fm], bf[fn], acc[fm][fn]);
      }
    }
  }

  // epilogue: PReLU + Wout reduce (over co = fm,j in-lane; l4 cross-lane)
  const float a  = pa[0];
  const float bo = bout[0];
  float wr_[4][4];
  #pragma unroll
  for (int fm = 0; fm < 4; ++fm)
    #pragma unroll
    for (int j = 0; j < 4; ++j)
      wr_[fm][j] = Wout[fm*16 + l4*4 + j];
  float* orow = out + ((size_t)((b*R_ + r)*H_ + h0 + wrow))*W_;
  #pragma unroll
  for (int fn = 0; fn < 4; ++fn) {
    float s = 0.f;
    #pragma unroll
    for (int fm = 0; fm < 4; ++fm)
      #pragma unroll
      for (int j = 0; j < 4; ++j) {
        float v = acc[fm][fn][j];
        v = (v >= 0.f) ? v : a*v;
        s += wr_[fm][j]*v;
      }
    s += __shfl_xor(s, 16, 64);
    s += __shfl_xor(s, 32, 64);
    if (lane < 16)
      orow[whalf*64 + fn*16 + lane] = s + bo;
  }
}

// ---------------------------------------------------------------------------
extern "C" void kernel_launch(void* const* d_in, const int* in_sizes, int n_in,
                              void* d_out, int out_size, void* d_ws, size_t ws_size,
                              hipStream_t stream) {
  (void)in_sizes; (void)n_in; (void)out_size; (void)ws_size;
  const float* x       = (const float*)d_in[0];
  const float* routing = (const float*)d_in[1];
  const float* rW      = (const float*)d_in[2];
  const float* rB      = (const float*)d_in[3];
  const float* W1      = (const float*)d_in[4];
  const float* pa      = (const float*)d_in[5];
  const float* W2      = (const float*)d_in[6];
  const float* srW     = (const float*)d_in[7];
  const float* srb     = (const float*)d_in[8];
  const float* Wout    = (const float*)d_in[9];
  const float* bout    = (const float*)d_in[10];
  float* out = (float*)d_out;

  char* ws = (char*)d_ws;
  size_t off = 0;
  f16_t* xbt = (f16_t*)(ws + off); off += (size_t)B_*H_*WP_*C_*2;     // 17,039,360
  f16_t* w1m = (f16_t*)(ws + off); off += (size_t)32*2*128*288*2;     //  4,718,592
  f16_t* xct = (f16_t*)(ws + off); off += (size_t)B_*H_*WP_*C2_*2;    // 34,078,720
  f16_t* w2m = (f16_t*)(ws + off); off += (size_t)B_*4*64*288*2;      //  1,179,648
  float* rw     = (float*)(ws + off); off += (size_t)R_*B_*E_*4;
  float* pooled = (float*)(ws + off); off += (size_t)R_*B_*C2_*4;     // per-r pooled
  // total ~57.1 MB of d_ws

  k_rw  <<<1, 256, 0, stream>>>(routing, rW, rB, rw, pooled);
  k_xt  <<<dim3(2, H_, B_), 256, 0, stream>>>(x, xbt);
  k_mix1<<<2304, 256, 0, stream>>>(rw, W1, w1m);
  for (int r = 0; r < R_; ++r) {
    float* pooled_r = pooled + (size_t)r*B_*C2_;
    k_conv1<<<dim3(32, B_), 512, 0, stream>>>(xbt, w1m, pa, xct, pooled_r, r);
    k_mix2 <<<576, 256, 0, stream>>>(pooled_r, srW, srb, W2, w2m);
    k_conv2<<<dim3(32, B_), 512, 0, stream>>>(xct, w2m, pa, Wout, bout, out, r);
  }
}

// Round 3
// 371.537 us; speedup vs baseline: 1.6623x; 1.1564x over previous
//
#include <hip/hip_runtime.h>
#include <stdint.h>

// ---------------------------------------------------------------------------
// DynamicConv (CondConv x2 + PReLU + self-routing + 1x1 out), MI355X gfx950
// R3: 80KB-LDS tiles -> 2 blocks/CU (TLP staging/MFMA overlap), coalesced
//     xct stores via LDS transpose, LDS cross-wave pooled reduce, setprio.
// ---------------------------------------------------------------------------

typedef _Float16 f16_t;
typedef _Float16 f16x8 __attribute__((ext_vector_type(8)));
typedef _Float16 f16x4 __attribute__((ext_vector_type(4)));
typedef float    f32x4 __attribute__((ext_vector_type(4)));

#define B_   8
#define R_   4
#define C_   64
#define C2_  128
#define H_   128
#define W_   128
#define E_   8
#define RF_  256
#define WP_  130   // padded width: guard cols at pix 0 and 129 (zeros)

#define A_PITCH 296   // f16 per co row: 9 taps * 32 ch + 8 pad (37 slots, 37%8=5)
#define B_PITCH 40    // f16 per (row,pix): 32 ch + 8 pad (5 slots)
#define XC_PITCH 72   // f16 per pixel in the store-transpose buffer (9 slots)

__device__ __forceinline__ f32x4 mfma16(f16x8 a, f16x8 b, f32x4 c) {
  return __builtin_amdgcn_mfma_f32_16x16x32_f16(a, b, c, 0, 0, 0);
}

// ---------- routing weights + zero pooled[4][B][C2] ----------
__global__ void k_rw(const float* __restrict__ routing, const float* __restrict__ rW,
                     const float* __restrict__ rB, float* __restrict__ rw,
                     float* __restrict__ pooled4) {
  int t = threadIdx.x;                 // 256 = R*B*E
  #pragma unroll
  for (int i = 0; i < 16; ++i) pooled4[i*256 + t] = 0.f;
  int e = t & 7, b = (t >> 3) & 7, r = t >> 6;
  float acc = rB[e];
  for (int f = 0; f < RF_; ++f)
    acc += routing[(b*R_ + r)*RF_ + f] * rW[f*E_ + e];
  rw[(r*B_ + b)*E_ + e] = 1.0f / (1.0f + __expf(-acc));
}

// ---------- x: NCHW f32 -> padded NHWC f16 (guard cols zeroed) ----------
__global__ void k_xt(const float* __restrict__ x, f16_t* __restrict__ xbt) {
  int wh = blockIdx.x, h = blockIdx.y, b = blockIdx.z;
  int t = threadIdx.x;
  int w0 = wh * 64;
  __shared__ float tile[64][65];
  #pragma unroll
  for (int rep = 0; rep < 16; ++rep) {
    int idx = rep*256 + t;
    int c = idx >> 6, w = idx & 63;
    tile[c][w] = x[((size_t)(b*C_ + c)*H_ + h)*W_ + w0 + w];
  }
  __syncthreads();
  #pragma unroll
  for (int rep = 0; rep < 16; ++rep) {
    int idx = rep*256 + t;
    int w = idx >> 6, c = idx & 63;
    xbt[((size_t)(b*H_ + h)*WP_ + (w0 + w + 1))*C_ + c] = (f16_t)tile[c][w];
  }
  if (t < 64) {
    if (wh == 0) xbt[((size_t)(b*H_ + h)*WP_ + 0)*C_ + t]   = (f16_t)0.0f;
    else         xbt[((size_t)(b*H_ + h)*WP_ + 129)*C_ + t] = (f16_t)0.0f;
  }
}

// ---------- mix1: w1m[rb][coh2][cb2][co64][s9][ch32] ----------
__global__ void k_mix1(const float* __restrict__ rw, const float* __restrict__ W1,
                       f16_t* __restrict__ w1m) {
  int gid = blockIdx.x*256 + threadIdx.x;    // 589824 total
  int cq = gid & 15;
  int s  = (gid >> 4) % 9;
  int t2 = (gid >> 4) / 9;
  int co = t2 & 127;
  int rb = t2 >> 7;                          // 0..31
  float o0=0.f,o1=0.f,o2=0.f,o3=0.f;
  #pragma unroll
  for (int e = 0; e < E_; ++e) {
    float rv = rw[rb*E_ + e];
    const float* wp = W1 + (size_t)((e*C2_ + co)*C_ + cq*4)*9 + s;
    o0 += rv*wp[0]; o1 += rv*wp[9]; o2 += rv*wp[18]; o3 += rv*wp[27];
  }
  f16x4 pk; pk[0]=(f16_t)o0; pk[1]=(f16_t)o1; pk[2]=(f16_t)o2; pk[3]=(f16_t)o3;
  int coh = co >> 6, co6 = co & 63;
  int cb = cq >> 3, cp = (cq & 7)*4;
  *(f16x4*)&w1m[((size_t)(((rb*2 + coh)*2 + cb)*64 + co6))*288 + s*32 + cp] = pk;
}

// ---------- mix2 (+inline srw): w2m[b][cb4][co64][s9][ch32] ----------
__global__ void k_mix2(const float* __restrict__ pooled_r, const float* __restrict__ srW,
                       const float* __restrict__ srb, const float* __restrict__ W2,
                       f16_t* __restrict__ w2m) {
  __shared__ float sw[64];
  int t = threadIdx.x;
  if (t < 64) {
    int b = t >> 3, e = t & 7;
    float acc = srb[e];
    for (int c = 0; c < C2_; ++c)
      acc += pooled_r[b*C2_ + c] * (1.0f/16384.0f) * srW[c*E_ + e];
    sw[t] = acc;
  }
  __syncthreads();
  int gid = blockIdx.x*256 + t;              // 147456 total
  int c2q = gid & 31;
  int s   = (gid >> 5) % 9;
  int t2  = (gid >> 5) / 9;
  int co  = t2 & 63;
  int b   = t2 >> 6;
  float o0=0.f,o1=0.f,o2=0.f,o3=0.f;
  #pragma unroll
  for (int e = 0; e < E_; ++e) {
    float rv = sw[b*E_ + e];
    const float* wp = W2 + (size_t)((e*C_ + co)*C2_ + c2q*4)*9 + s;
    o0 += rv*wp[0]; o1 += rv*wp[9]; o2 += rv*wp[18]; o3 += rv*wp[27];
  }
  f16x4 pk; pk[0]=(f16_t)o0; pk[1]=(f16_t)o1; pk[2]=(f16_t)o2; pk[3]=(f16_t)o3;
  int cb = c2q >> 3, cp = (c2q & 7)*4;
  *(f16x4*)&w2m[((size_t)((b*4 + cb)*64 + co))*288 + s*32 + cp] = pk;
}

// ---------- conv1: block (b, 2 rows, co-half): M=64 x N=256 x K=576 ----------
__global__ __launch_bounds__(256, 2) void k_conv1(
    const f16_t* __restrict__ xbt, const f16_t* __restrict__ w1m,
    const float* __restrict__ pa, f16_t* __restrict__ xct,
    float* __restrict__ pooled_r, int r)
{
  const int b   = blockIdx.y;
  const int h0  = blockIdx.x * 2;
  const int coh = blockIdx.z;
  const int tid = threadIdx.x;
  const int lane = tid & 63;
  const int wid = tid >> 6;                  // 0..3
  const int wrow = wid >> 1, wph = wid & 1;  // output row, pixel half
  const int l15 = lane & 15, l4 = lane >> 4;
  __shared__ __align__(16) f16_t lA[64 * A_PITCH];   // 37,888 B
  __shared__ __align__(16) f16_t lB[520 * B_PITCH];  // 41,600 B  (total 79,488)
  const f32x4 vzero = {0.f,0.f,0.f,0.f};
  f32x4 acc[4][4];
  #pragma unroll
  for (int i=0;i<4;++i)
    #pragma unroll
    for (int j=0;j<4;++j) acc[i][j] = vzero;
  const int rb = r*B_ + b;
  const f16_t* w1base = w1m + ((size_t)(rb*2 + coh)*2)*64*288;
  const f16_t* xb = xbt + (size_t)b*H_*WP_*C_;

  for (int cb = 0; cb < 2; ++cb) {
    __syncthreads();
    // stage A: 64co x 288 f16 = 2304 x 16B slots (9 per thread)
    #pragma unroll
    for (int it = 0; it < 9; ++it) {
      int i = it*256 + tid;
      int co = i / 36, u = i - co*36;
      uint4 v = *(const uint4*)(w1base + ((size_t)(cb*64 + co))*288 + u*8);
      *(uint4*)&lA[co*A_PITCH + u*8] = v;
    }
    // stage B: 4 rows x 130 pix x 32 ch = 2080 slots (zero OOB rows)
    for (int i = tid; i < 2080; i += 256) {
      int rp = i >> 2, q = i & 3;
      int wr2 = rp / 130, pix = rp - wr2*130;
      int hh = h0 - 1 + wr2;
      uint4 v = {0u,0u,0u,0u};
      if (hh >= 0 && hh < H_)
        v = *(const uint4*)(xb + ((size_t)hh*WP_ + pix)*C_ + cb*32 + q*8);
      *(uint4*)&lB[rp*B_PITCH + q*8] = v;
    }
    __syncthreads();
    __builtin_amdgcn_s_setprio(1);
    #pragma unroll
    for (int dh = 0; dh < 3; ++dh) {
      #pragma unroll
      for (int dw = 0; dw < 3; ++dw) {
        const int s = dh*3 + dw;
        f16x8 af[4], bf[4];
        #pragma unroll
        for (int fm = 0; fm < 4; ++fm)
          af[fm] = *(const f16x8*)&lA[(fm*16 + l15)*A_PITCH + s*32 + l4*8];
        #pragma unroll
        for (int fn = 0; fn < 4; ++fn)
          bf[fn] = *(const f16x8*)&lB[((wrow + dh)*130 + wph*64 + fn*16 + l15 + dw)*B_PITCH + l4*8];
        #pragma unroll
        for (int fm = 0; fm < 4; ++fm)
          #pragma unroll
          for (int fn = 0; fn < 4; ++fn)
            acc[fm][fn] = mfma16(af[fm], bf[fn], acc[fm][fn]);
      }
    }
    __builtin_amdgcn_s_setprio(0);
  }

  // epilogue: PReLU in-place, pooled partials, transpose-store via LDS
  const float a = pa[0];
  float ps[4][4];
  #pragma unroll
  for (int fm=0;fm<4;++fm)
    #pragma unroll
    for (int j=0;j<4;++j) ps[fm][j] = 0.f;
  #pragma unroll
  for (int fm = 0; fm < 4; ++fm)
    #pragma unroll
    for (int fn = 0; fn < 4; ++fn)
      #pragma unroll
      for (int j = 0; j < 4; ++j) {
        float v = acc[fm][fn][j];
        v = (v >= 0.f) ? v : a*v;
        acc[fm][fn][j] = v;
        ps[fm][j] += v;
      }
  #pragma unroll
  for (int fm = 0; fm < 4; ++fm)
    #pragma unroll
    for (int j = 0; j < 4; ++j) {
      float s = ps[fm][j];
      s += __shfl_xor(s, 1, 64);
      s += __shfl_xor(s, 2, 64);
      s += __shfl_xor(s, 4, 64);
      s += __shfl_xor(s, 8, 64);
      ps[fm][j] = s;                 // valid on l15==0 lanes
    }
  __syncthreads();                   // done reading lA/lB for MFMA
  // scatter acc into lB as [pix_local 256][XC_PITCH]
  f16_t* lso = lB;
  const int prow = wrow*128 + wph*64;
  #pragma unroll
  for (int fm = 0; fm < 4; ++fm)
    #pragma unroll
    for (int fn = 0; fn < 4; ++fn) {
      f16x4 pk;
      #pragma unroll
      for (int j = 0; j < 4; ++j) pk[j] = (f16_t)acc[fm][fn][j];
      *(f16x4*)&lso[(prow + fn*16 + l15)*XC_PITCH + fm*16 + l4*4] = pk;
    }
  float* lps = (float*)lA;           // 4 waves x 64 ch partial pooled sums
  if (l15 == 0) {
    #pragma unroll
    for (int fm = 0; fm < 4; ++fm)
      #pragma unroll
      for (int j = 0; j < 4; ++j)
        lps[wid*64 + fm*16 + l4*4 + j] = ps[fm][j];
  }
  __syncthreads();
  // coalesced global store: 256 pix x 128B half-rows
  #pragma unroll
  for (int p = 0; p < 8; ++p) {
    int i = p*256 + tid;
    int pl = i >> 3, q = i & 7;
    int row = pl >> 7, pix = pl & 127;
    uint4 v = *(const uint4*)&lso[pl*XC_PITCH + q*8];
    *(uint4*)(xct + ((size_t)(b*H_ + h0 + row)*WP_ + pix + 1)*C2_ + coh*64 + q*8) = v;
  }
  // pooled: one atomic per channel per block
  if (tid < 64) {
    float s = lps[tid] + lps[64 + tid] + lps[128 + tid] + lps[192 + tid];
    atomicAdd(&pooled_r[b*C2_ + coh*64 + tid], s);
  }
  // zero guard columns (pix 0 and 129) for our co-half, both rows
  {
    int row = tid >> 7, pixsel = (tid >> 6) & 1, ch = tid & 63;
    xct[((size_t)(b*H_ + h0 + row)*WP_ + pixsel*129)*C2_ + coh*64 + ch] = (f16_t)0.f;
  }
}

// ---------- conv2 + PReLU + 1x1 Wout: block (b, 2 rows): 64 x 256 x 1152 ----
__global__ __launch_bounds__(256, 2) void k_conv2(
    const f16_t* __restrict__ xct, const f16_t* __restrict__ w2m,
    const float* __restrict__ pa, const float* __restrict__ Wout,
    const float* __restrict__ bout, float* __restrict__ out, int r)
{
  const int b  = blockIdx.y;
  const int h0 = blockIdx.x * 2;
  const int tid = threadIdx.x;
  const int lane = tid & 63;
  const int wid = tid >> 6;
  const int wrow = wid >> 1, wph = wid & 1;
  const int l15 = lane & 15, l4 = lane >> 4;
  __shared__ __align__(16) f16_t lA[64 * A_PITCH];   // 37,888 B
  __shared__ __align__(16) f16_t lB[520 * B_PITCH];  // 41,600 B
  const f32x4 vzero = {0.f,0.f,0.f,0.f};
  f32x4 acc[4][4];
  #pragma unroll
  for (int i=0;i<4;++i)
    #pragma unroll
    for (int j=0;j<4;++j) acc[i][j] = vzero;
  const f16_t* w2base = w2m + (size_t)b*4*64*288;
  const f16_t* xb = xct + (size_t)b*H_*WP_*C2_;

  for (int cb = 0; cb < 4; ++cb) {
    __syncthreads();
    // stage A: 2304 slots
    #pragma unroll
    for (int it = 0; it < 9; ++it) {
      int i = it*256 + tid;
      int co = i / 36, u = i - co*36;
      uint4 v = *(const uint4*)(w2base + ((size_t)(cb*64 + co))*288 + u*8);
      *(uint4*)&lA[co*A_PITCH + u*8] = v;
    }
    // stage B: 4 rows x 130 pix x 32 ch
    for (int i = tid; i < 2080; i += 256) {
      int rp = i >> 2, q = i & 3;
      int wr2 = rp / 130, pix = rp - wr2*130;
      int hh = h0 - 1 + wr2;
      uint4 v = {0u,0u,0u,0u};
      if (hh >= 0 && hh < H_)
        v = *(const uint4*)(xb + ((size_t)hh*WP_ + pix)*C2_ + cb*32 + q*8);
      *(uint4*)&lB[rp*B_PITCH + q*8] = v;
    }
    __syncthreads();
    __builtin_amdgcn_s_setprio(1);
    #pragma unroll
    for (int dh = 0; dh < 3; ++dh) {
      #pragma unroll
      for (int dw = 0; dw < 3; ++dw) {
        const int s = dh*3 + dw;
        f16x8 af[4], bf[4];
        #pragma unroll
        for (int fm = 0; fm < 4; ++fm)
          af[fm] = *(const f16x8*)&lA[(fm*16 + l15)*A_PITCH + s*32 + l4*8];
        #pragma unroll
        for (int fn = 0; fn < 4; ++fn)
          bf[fn] = *(const f16x8*)&lB[((wrow + dh)*130 + wph*64 + fn*16 + l15 + dw)*B_PITCH + l4*8];
        #pragma unroll
        for (int fm = 0; fm < 4; ++fm)
          #pragma unroll
          for (int fn = 0; fn < 4; ++fn)
            acc[fm][fn] = mfma16(af[fm], bf[fn], acc[fm][fn]);
      }
    }
    __builtin_amdgcn_s_setprio(0);
  }

  // epilogue: PReLU + Wout reduce
  const float a  = pa[0];
  const float bo = bout[0];
  float wr_[4][4];
  #pragma unroll
  for (int fm = 0; fm < 4; ++fm)
    #pragma unroll
    for (int j = 0; j < 4; ++j)
      wr_[fm][j] = Wout[fm*16 + l4*4 + j];
  float* orow = out + ((size_t)((b*R_ + r)*H_ + h0 + wrow))*W_;
  #pragma unroll
  for (int fn = 0; fn < 4; ++fn) {
    float s = 0.f;
    #pragma unroll
    for (int fm = 0; fm < 4; ++fm)
      #pragma unroll
      for (int j = 0; j < 4; ++j) {
        float v = acc[fm][fn][j];
        v = (v >= 0.f) ? v : a*v;
        s += wr_[fm][j]*v;
      }
    s += __shfl_xor(s, 16, 64);
    s += __shfl_xor(s, 32, 64);
    if (lane < 16)
      orow[wph*64 + fn*16 + lane] = s + bo;
  }
}

// ---------------------------------------------------------------------------
extern "C" void kernel_launch(void* const* d_in, const int* in_sizes, int n_in,
                              void* d_out, int out_size, void* d_ws, size_t ws_size,
                              hipStream_t stream) {
  (void)in_sizes; (void)n_in; (void)out_size; (void)ws_size;
  const float* x       = (const float*)d_in[0];
  const float* routing = (const float*)d_in[1];
  const float* rW      = (const float*)d_in[2];
  const float* rB      = (const float*)d_in[3];
  const float* W1      = (const float*)d_in[4];
  const float* pa      = (const float*)d_in[5];
  const float* W2      = (const float*)d_in[6];
  const float* srW     = (const float*)d_in[7];
  const float* srb     = (const float*)d_in[8];
  const float* Wout    = (const float*)d_in[9];
  const float* bout    = (const float*)d_in[10];
  float* out = (float*)d_out;

  char* ws = (char*)d_ws;
  size_t off = 0;
  f16_t* xbt = (f16_t*)(ws + off); off += (size_t)B_*H_*WP_*C_*2;     // 17,039,360
  f16_t* w1m = (f16_t*)(ws + off); off += (size_t)32*2*2*64*288*2;    //  4,718,592
  f16_t* xct = (f16_t*)(ws + off); off += (size_t)B_*H_*WP_*C2_*2;    // 34,078,720
  f16_t* w2m = (f16_t*)(ws + off); off += (size_t)B_*4*64*288*2;      //  1,179,648
  float* rw     = (float*)(ws + off); off += (size_t)R_*B_*E_*4;
  float* pooled = (float*)(ws + off); off += (size_t)R_*B_*C2_*4;     // per-r pooled
  // total ~57.1 MB of d_ws

  k_rw  <<<1, 256, 0, stream>>>(routing, rW, rB, rw, pooled);
  k_xt  <<<dim3(2, H_, B_), 256, 0, stream>>>(x, xbt);
  k_mix1<<<2304, 256, 0, stream>>>(rw, W1, w1m);
  for (int r = 0; r < R_; ++r) {
    float* pooled_r = pooled + (size_t)r*B_*C2_;
    k_conv1<<<dim3(64, B_, 2), 256, 0, stream>>>(xbt, w1m, pa, xct, pooled_r, r);
    k_mix2 <<<576, 256, 0, stream>>>(pooled_r, srW, srb, W2, w2m);
    k_conv2<<<dim3(64, B_), 256, 0, stream>>>(xct, w2m, pa, Wout, bout, out, r);
  }
}